// Round 1
// 1424.624 us; speedup vs baseline: 1.0318x; 1.0318x over previous
//
#include <hip/hip_runtime.h>
#include <cstdint>
#include <cstddef>

// BotGAT forward, MI355X (gfx950). Round 3.
// Change vs round 2: k_enc restaged through LDS via global_load_lds(16B),
// double-buffered, per-wave-private tiles (no __syncthreads), XOR-chunk
// swizzle applied on the global SOURCE addresses + same XOR on LDS reads
// (linear DMA dest per HW constraint). Goal: raise loads-in-flight per CU
// from ~1.6KB to ~64KB to reach the HBM roofline (k_enc 250us -> ~110us).
// All other kernels unchanged.

typedef __bf16 bf16x8 __attribute__((ext_vector_type(8)));
typedef float f32x4 __attribute__((ext_vector_type(4)));
typedef unsigned short u16x4 __attribute__((ext_vector_type(4)));

static __device__ __forceinline__ float bf2f(unsigned short u){
    unsigned int x = ((unsigned int)u) << 16;
    return __builtin_bit_cast(float, x);
}
static __device__ __forceinline__ unsigned short f2bf(float f){
    unsigned int u = __builtin_bit_cast(unsigned int, f);
    unsigned int r = u + 0x7fffu + ((u >> 16) & 1u);   // RNE
    return (unsigned short)(r >> 16);
}
static __device__ __forceinline__ void splitf(float v, unsigned short& h, unsigned short& l){
    h = f2bf(v);
    l = f2bf(v - bf2f(h));
}
static __device__ __forceinline__ float leaky01(float v){ return v > 0.f ? v : 0.01f * v; }
static __device__ __forceinline__ float leaky02(float v){ return v > 0.f ? v : 0.2f  * v; }

static __device__ __forceinline__ void gload16(const float* g, const void* l){
    __builtin_amdgcn_global_load_lds(
        (const __attribute__((address_space(1))) void*)g,
        (__attribute__((address_space(3))) void*)l, 16, 0, 0);
}

// ---------------------------------------------------------------------------
// Edge-index dtype detection: int64 arrays (values in [0,N)) have every odd
// int32 word == 0. Flag = element stride in int32 units (1 or 2).
// ---------------------------------------------------------------------------
__global__ void k_detect(const int* __restrict__ ei32, int* __restrict__ eflag){
    int t = threadIdx.x;                      // 64 threads
    int v = ei32[2*t + 1];
    unsigned long long nz = __ballot(v != 0);
    if (t == 0) eflag[0] = (nz == 0ull) ? 2 : 1;
}

// ---------------------------------------------------------------------------
// Weight prep: split f32 weights into bf16 hi/lo, transposed layouts.
// encW: [mod][hl][c(32)][k(768)] ushort  (per mod: 2*24576 = 49152 elems)
// ---------------------------------------------------------------------------
__global__ __launch_bounds__(256) void k_prep_enc(
    const float* __restrict__ Wd, const float* __restrict__ Wtw,
    unsigned short* __restrict__ encW)
{
    int idx = blockIdx.x * 256 + threadIdx.x;
    if (idx >= 2*24576) return;
    int mod = idx / 24576, r = idx % 24576;
    int c = r / 768, k = r % 768;
    const float* W = mod ? Wtw : Wd;
    unsigned short h, l; splitf(W[(size_t)k*32 + c], h, l);
    encW[(size_t)mod*49152 + c*768 + k]         = h;
    encW[(size_t)mod*49152 + 24576 + c*768 + k] = l;
}
// midW: [mat(4)][hl][ c*128 + ((k>>3)^(c&15))*8 + (k&7) ]  (per mat: 32768 elems)
__global__ __launch_bounds__(256) void k_prep_mid(
    const float* __restrict__ W0, const float* __restrict__ W1,
    const float* __restrict__ W2, const float* __restrict__ W3,
    unsigned short* __restrict__ midW)
{
    int idx = blockIdx.x * 256 + threadIdx.x;
    if (idx >= 4*16384) return;
    int m = idx / 16384, r = idx % 16384;
    int k = r >> 7, c = r & 127;
    const float* W = m == 0 ? W0 : m == 1 ? W1 : m == 2 ? W2 : W3;
    unsigned short h, l; splitf(W[(size_t)k*128 + c], h, l);
    int g = (k >> 3) ^ (c & 15);
    size_t base = (size_t)m * 32768;
    midW[base + c*128 + g*8 + (k & 7)]         = h;
    midW[base + 16384 + c*128 + g*8 + (k & 7)] = l;
}

// ---------------------------------------------------------------------------
// Encoder: x0[:, colofs..colofs+31] = leaky01(A[N,768] @ W[768,32] + b)
// A staged to LDS via global_load_lds(16B), double-buffered, 64 rows/block,
// K-step 64. Each wave owns rows wave*16..wave*16+15 and stages ONLY those
// rows -> no __syncthreads; per-wave vmcnt(0) pipelining.
// LDS layout: buffer b, float offset = row*64 + (chunk^(row&15))*16B where
// chunk = logical 16B chunk (4 floats). Source addresses pre-swizzled with
// the same XOR so the linear DMA write lands swizzled (rule: both-sides).
// ---------------------------------------------------------------------------
__global__ __launch_bounds__(256, 4) void k_enc(
    const float* __restrict__ des, const float* __restrict__ bd,
    const float* __restrict__ twt, const float* __restrict__ bt,
    const unsigned short* __restrict__ encW,
    float* __restrict__ x0, int n)
{
    __shared__ float As[2][64*64];       // 2 x 16KB double buffer

    const float* A; const float* bias; int colofs; const unsigned short* Wb;
    if (blockIdx.y == 0){ A = des; bias = bd; colofs = 0;  Wb = encW; }
    else                { A = twt; bias = bt; colofs = 32; Wb = encW + 49152; }

    int lane = threadIdx.x & 63, wave = threadIdx.x >> 6;
    int rowBase = blockIdx.x * 64;

    // staging source pointers: instruction inst covers physical chunks
    // p = (wave*4+inst)*64 + lane ->
    //   row = wave*16 + inst*4 + (lane>>4), physchunk = lane&15,
    //   logical chunk = physchunk ^ (row&15), row&15 = inst*4 + (lane>>4)
    const float* ap0; const float* ap1; const float* ap2; const float* ap3;
    {
        const float* tmp[4];
        #pragma unroll
        for (int inst = 0; inst < 4; ++inst){
            int row = wave*16 + inst*4 + (lane >> 4);
            int gr = rowBase + row; if (gr >= n) gr = n - 1;
            int lc = (lane & 15) ^ (inst*4 + (lane >> 4));
            tmp[inst] = A + (size_t)gr*768 + lc*4;
        }
        ap0 = tmp[0]; ap1 = tmp[1]; ap2 = tmp[2]; ap3 = tmp[3];
    }

    int mr = lane & 15;
    int j  = lane >> 4;                  // k-group within MFMA fragment
    const unsigned short* W0p = Wb + mr*768 + j*8;
    const unsigned short* W1p = Wb + (16 + mr)*768 + j*8;

    f32x4 acc0 = {0.f,0.f,0.f,0.f}, acc1 = {0.f,0.f,0.f,0.f};
    int r = wave*16 + mr;                // logical row this lane reads for MFMA A

    // prologue: stage K-step 0 into buffer 0
    {
        char* lb = (char*)(&As[0][0]) + wave*4096;
        gload16(ap0,       lb);
        gload16(ap1,       lb + 1024);
        gload16(ap2,       lb + 2048);
        gload16(ap3,       lb + 3072);
    }

    for (int t = 0; t < 12; ++t){
        // wait for buffer t&1 (and any stragglers); then prefetch t+1
        asm volatile("s_waitcnt vmcnt(0)" ::: "memory");
        __builtin_amdgcn_sched_barrier(0);
        if (t < 11){
            int k1 = (t + 1) * 64;
            char* lb = (char*)(&As[(t + 1) & 1][0]) + wave*4096;
            gload16(ap0 + k1, lb);
            gload16(ap1 + k1, lb + 1024);
            gload16(ap2 + k1, lb + 2048);
            gload16(ap3 + k1, lb + 3072);
        }
        const float* Ab = &As[t & 1][0] + r*64;
        int k0 = t * 64;
        #pragma unroll
        for (int half = 0; half < 2; ++half){
            int lc0 = half*8 + 2*j;
            f32x4 a0 = *(const f32x4*)(Ab + ((lc0       ^ mr) * 4));
            f32x4 a1 = *(const f32x4*)(Ab + (((lc0 + 1) ^ mr) * 4));
            bf16x8 ah, al;
            #pragma unroll
            for (int i = 0; i < 4; ++i){
                unsigned short h, l; splitf(a0[i], h, l);
                ah[i] = __builtin_bit_cast(__bf16, h);
                al[i] = __builtin_bit_cast(__bf16, l);
            }
            #pragma unroll
            for (int i = 0; i < 4; ++i){
                unsigned short h, l; splitf(a1[i], h, l);
                ah[4+i] = __builtin_bit_cast(__bf16, h);
                al[4+i] = __builtin_bit_cast(__bf16, l);
            }
            int kk = k0 + half*32;
            bf16x8 b0h = *(const bf16x8*)(W0p + kk);
            bf16x8 b0l = *(const bf16x8*)(W0p + 24576 + kk);
            bf16x8 b1h = *(const bf16x8*)(W1p + kk);
            bf16x8 b1l = *(const bf16x8*)(W1p + 24576 + kk);
            acc0 = __builtin_amdgcn_mfma_f32_16x16x32_bf16(ah, b0h, acc0, 0, 0, 0);
            acc0 = __builtin_amdgcn_mfma_f32_16x16x32_bf16(al, b0h, acc0, 0, 0, 0);
            acc0 = __builtin_amdgcn_mfma_f32_16x16x32_bf16(ah, b0l, acc0, 0, 0, 0);
            acc1 = __builtin_amdgcn_mfma_f32_16x16x32_bf16(ah, b1h, acc1, 0, 0, 0);
            acc1 = __builtin_amdgcn_mfma_f32_16x16x32_bf16(al, b1h, acc1, 0, 0, 0);
            acc1 = __builtin_amdgcn_mfma_f32_16x16x32_bf16(ah, b1l, acc1, 0, 0, 0);
        }
    }

    float bc0 = bias[mr];
    float bc1 = bias[16 + mr];
    int r0 = rowBase + wave*16 + (j << 2);
    #pragma unroll
    for (int rr4 = 0; rr4 < 4; ++rr4){
        int rr = r0 + rr4;
        if (rr < n){
            x0[(size_t)rr*128 + colofs + mr]      = leaky01(acc0[rr4] + bc0);
            x0[(size_t)rr*128 + colofs + 16 + mr] = leaky01(acc1[rr4] + bc1);
        }
    }
}

// ---------------------------------------------------------------------------
// num_prop/cat_prop encoders -> x0 columns 64..127 (tiny K, fp32 exact)
// ---------------------------------------------------------------------------
__global__ __launch_bounds__(256) void k_npcp(
    const float* __restrict__ npv, const float* __restrict__ Wnp,
    const float* __restrict__ bnp,
    const float* __restrict__ cpv, const float* __restrict__ Wcp,
    const float* __restrict__ bcp,
    float* __restrict__ x0, int n)
{
    __shared__ float w5[160], w3[96], bb[64];
    int tid = threadIdx.x;
    if (tid < 160) w5[tid] = Wnp[tid];
    if (tid >= 160 && tid < 256) w3[tid - 160] = Wcp[tid - 160];
    if (tid < 32) bb[tid] = bnp[tid];
    if (tid >= 32 && tid < 64) bb[tid] = bcp[tid - 32];
    __syncthreads();

    int node = blockIdx.x * 256 + tid;
    if (node >= n) return;
    float a[5], b3[3];
    #pragma unroll
    for (int i = 0; i < 5; ++i) a[i] = npv[(size_t)node*5 + i];
    #pragma unroll
    for (int i = 0; i < 3; ++i) b3[i] = cpv[(size_t)node*3 + i];
    float* xo = x0 + (size_t)node * 128;
    #pragma unroll
    for (int c = 0; c < 32; c += 4){
        f32x4 o1, o2;
        #pragma unroll
        for (int u = 0; u < 4; ++u){
            float s = bb[c + u];
            #pragma unroll
            for (int i = 0; i < 5; ++i) s += a[i] * w5[i*32 + c + u];
            o1[u] = leaky01(s);
            float t = bb[32 + c + u];
            #pragma unroll
            for (int i = 0; i < 3; ++i) t += b3[i] * w3[i*32 + c + u];
            o2[u] = leaky01(t);
        }
        *(f32x4*)(xo + 64 + c) = o1;
        *(f32x4*)(xo + 96 + c) = o2;
    }
}

// ---------------------------------------------------------------------------
// Mid GEMM: C[N,128] = A[N,128](f32) @ W[128,128](f32, pre-split hi/lo bf16
// in midWm). A split into LDS (XOR-swizzled, conflict-free b128 reads).
// act=1: += bias, leaky01.
// ---------------------------------------------------------------------------
__global__ __launch_bounds__(256) void k_mid(
    const float* __restrict__ A, const unsigned short* __restrict__ midWm,
    const float* __restrict__ bias, float* __restrict__ C, int n, int act)
{
    __shared__ unsigned short Ah[64*128];
    __shared__ unsigned short Al[64*128];
    int tid = threadIdx.x;
    int rowBase = blockIdx.x * 64;
    for (int q = tid; q < 64*32; q += 256){
        int r = q >> 5, c4 = (q & 31) * 4;
        int gr = rowBase + r; if (gr >= n) gr = n - 1;
        f32x4 v = *(const f32x4*)(A + (size_t)gr*128 + c4);
        unsigned short hh[4], ll[4];
        #pragma unroll
        for (int i = 0; i < 4; ++i) splitf(v[i], hh[i], ll[i]);
        int g = (c4 >> 3) ^ (r & 15);
        int off = r*128 + g*8 + (c4 & 7);
        u16x4 th = {hh[0], hh[1], hh[2], hh[3]};
        u16x4 tl = {ll[0], ll[1], ll[2], ll[3]};
        *(u16x4*)(&Ah[off]) = th;
        *(u16x4*)(&Al[off]) = tl;
    }
    __syncthreads();

    int lane = tid & 63, wave = tid >> 6;
    int mr = lane & 15;
    int kg = (lane >> 4) * 8;
    int wrow = wave * 16 + mr;
    f32x4 acc[8];
    #pragma unroll
    for (int i = 0; i < 8; ++i) acc[i] = (f32x4){0.f,0.f,0.f,0.f};

    #pragma unroll
    for (int k0 = 0; k0 < 128; k0 += 32){
        int gidx = (k0 + kg) >> 3;
        int aoff = wrow*128 + ((gidx ^ mr) * 8);
        bf16x8 ahf = *(const bf16x8*)(&Ah[aoff]);
        bf16x8 alf = *(const bf16x8*)(&Al[aoff]);
        #pragma unroll
        for (int ct = 0; ct < 8; ++ct){
            int brow = ct*16 + mr;
            int woff = brow*128 + ((gidx ^ mr) * 8);
            bf16x8 bh = *(const bf16x8*)(midWm + woff);
            bf16x8 bl = *(const bf16x8*)(midWm + 16384 + woff);
            acc[ct] = __builtin_amdgcn_mfma_f32_16x16x32_bf16(ahf, bh, acc[ct], 0, 0, 0);
            acc[ct] = __builtin_amdgcn_mfma_f32_16x16x32_bf16(alf, bh, acc[ct], 0, 0, 0);
            acc[ct] = __builtin_amdgcn_mfma_f32_16x16x32_bf16(ahf, bl, acc[ct], 0, 0, 0);
        }
    }

    int r0 = rowBase + wave*16 + ((lane >> 4) << 2);
    #pragma unroll
    for (int ct = 0; ct < 8; ++ct){
        int cc = ct*16 + mr;
        float bv = act ? bias[cc] : 0.f;
        #pragma unroll
        for (int rr4 = 0; rr4 < 4; ++rr4){
            int rr = r0 + rr4;
            if (rr < n){
                float v = acc[ct][rr4] + bv;
                if (act) v = leaky01(v);
                C[(size_t)rr*128 + cc] = v;
            }
        }
    }
}

// ---------------------------------------------------------------------------
// Attention coefficients: al_s[n][h] = sum_c h[n,h*32+c]*a_src[h,c]
// ---------------------------------------------------------------------------
__global__ __launch_bounds__(256) void k_al(
    const float* __restrict__ h, const float* __restrict__ a_src,
    const float* __restrict__ a_dst, float* __restrict__ als,
    float* __restrict__ ald, int n, int heads)
{
    int lane = threadIdx.x & 63, wave = threadIdx.x >> 6;
    int node = blockIdx.x * 4 + wave;
    if (node >= n) return;
    float2 hv = *(const float2*)(h + (size_t)node*128 + lane*2);
    float2 asv = *(const float2*)(a_src + lane*2);
    float2 adv = *(const float2*)(a_dst + lane*2);
    float ps = hv.x*asv.x + hv.y*asv.y;
    float pd = hv.x*adv.x + hv.y*adv.y;
    #pragma unroll
    for (int ofs = 1; ofs <= 8; ofs <<= 1){
        ps += __shfl_xor(ps, ofs);
        pd += __shfl_xor(pd, ofs);
    }
    if (heads == 1){
        ps += __shfl_xor(ps, 16); pd += __shfl_xor(pd, 16);
        ps += __shfl_xor(ps, 32); pd += __shfl_xor(pd, 32);
        if (lane == 0){ als[node] = ps; ald[node] = pd; }
    } else {
        if ((lane & 15) == 0){
            als[(size_t)node*4 + (lane >> 4)] = ps;
            ald[(size_t)node*4 + (lane >> 4)] = pd;
        }
    }
}

// ---------------------------------------------------------------------------
// GAT edge softmax + aggregation, 4 heads. Wave per dst node; self-loop
// analytic. Lane j preloads edge j; shuffles broadcast weights in pass 2.
// ---------------------------------------------------------------------------
__global__ __launch_bounds__(256) void k_edge4(
    const float* __restrict__ h, const float* __restrict__ als, const float* __restrict__ ald,
    const int* __restrict__ startv, const int* __restrict__ degv, const int* __restrict__ col,
    const float* __restrict__ bias, float* __restrict__ outp, int n)
{
    int lane = threadIdx.x & 63, wave = threadIdx.x >> 6;
    int node = blockIdx.x * 4 + wave;
    if (node >= n) return;
    int hl = lane >> 4;
    int st = startv[node], dg = degv[node];
    f32x4 sAls = *(const f32x4*)(als + (size_t)node*4);
    f32x4 sAld = *(const f32x4*)(ald + (size_t)node*4);
    float es[4], m[4];
    #pragma unroll
    for (int t = 0; t < 4; ++t){ es[t] = leaky02(sAls[t] + sAld[t]); m[t] = es[t]; }

    int mycol = 0; f32x4 myals = {0.f,0.f,0.f,0.f};
    bool have = lane < dg;
    if (have){
        mycol = col[st + lane];
        myals = *(const f32x4*)(als + (size_t)mycol*4);
    }
    float e4[4];
    #pragma unroll
    for (int t = 0; t < 4; ++t){
        e4[t] = have ? leaky02(myals[t] + sAld[t]) : -3.0e38f;
        m[t] = fmaxf(m[t], e4[t]);
    }
    #pragma unroll
    for (int ofs = 1; ofs <= 32; ofs <<= 1){
        #pragma unroll
        for (int t = 0; t < 4; ++t) m[t] = fmaxf(m[t], __shfl_xor(m[t], ofs));
    }
    float w4[4];
    #pragma unroll
    for (int t = 0; t < 4; ++t) w4[t] = have ? __expf(e4[t] - m[t]) : 0.f;

    float wself = __expf(es[hl] - m[hl]);
    float den = wself;
    float2 hs = *(const float2*)(h + (size_t)node*128 + lane*2);
    float acc0 = wself * hs.x, acc1 = wself * hs.y;

    int nin = dg < 64 ? dg : 64;
    for (int jj = 0; jj < nin; ++jj){
        int s = __shfl(mycol, jj);
        float wv0 = __shfl(w4[0], jj), wv1 = __shfl(w4[1], jj);
        float wv2 = __shfl(w4[2], jj), wv3 = __shfl(w4[3], jj);
        float wgt = hl == 0 ? wv0 : hl == 1 ? wv1 : hl == 2 ? wv2 : wv3;
        float2 hv = *(const float2*)(h + (size_t)s*128 + lane*2);
        den += wgt;
        acc0 += wgt * hv.x; acc1 += wgt * hv.y;
    }
    for (int jj = 64; jj < dg; ++jj){   // Poisson(16) tail beyond 64: ~never
        int s = col[st + jj];
        float asv = als[(size_t)s*4 + hl];
        float wgt = __expf(leaky02(asv + sAld[hl]) - m[hl]);
        float2 hv = *(const float2*)(h + (size_t)s*128 + lane*2);
        den += wgt; acc0 += wgt * hv.x; acc1 += wgt * hv.y;
    }
    float inv = 1.0f / (den + 1e-16f);
    float2 bv = *(const float2*)(bias + lane*2);
    float2 o; o.x = acc0 * inv + bv.x; o.y = acc1 * inv + bv.y;
    *(float2*)(outp + (size_t)node*128 + lane*2) = o;
}

// Same, 1 head / 128 channels.
__global__ __launch_bounds__(256) void k_edge1(
    const float* __restrict__ h, const float* __restrict__ als, const float* __restrict__ ald,
    const int* __restrict__ startv, const int* __restrict__ degv, const int* __restrict__ col,
    const float* __restrict__ bias, float* __restrict__ outp, int n)
{
    int lane = threadIdx.x & 63, wave = threadIdx.x >> 6;
    int node = blockIdx.x * 4 + wave;
    if (node >= n) return;
    int st = startv[node], dg = degv[node];
    float sa = als[node], sd = ald[node];
    float es = leaky02(sa + sd);
    float m = es;
    int mycol = 0; float myals = 0.f;
    bool have = lane < dg;
    if (have){ mycol = col[st + lane]; myals = als[mycol]; }
    float e1 = have ? leaky02(myals + sd) : -3.0e38f;
    m = fmaxf(m, e1);
    #pragma unroll
    for (int ofs = 1; ofs <= 32; ofs <<= 1) m = fmaxf(m, __shfl_xor(m, ofs));
    float w1 = have ? __expf(e1 - m) : 0.f;

    float wself = __expf(es - m);
    float den = wself;
    float2 hs = *(const float2*)(h + (size_t)node*128 + lane*2);
    float acc0 = wself * hs.x, acc1 = wself * hs.y;

    int nin = dg < 64 ? dg : 64;
    for (int jj = 0; jj < nin; ++jj){
        int s = __shfl(mycol, jj);
        float wgt = __shfl(w1, jj);
        float2 hv = *(const float2*)(h + (size_t)s*128 + lane*2);
        den += wgt; acc0 += wgt * hv.x; acc1 += wgt * hv.y;
    }
    for (int jj = 64; jj < dg; ++jj){
        int s = col[st + jj];
        float wgt = __expf(leaky02(als[s] + sd) - m);
        float2 hv = *(const float2*)(h + (size_t)s*128 + lane*2);
        den += wgt; acc0 += wgt * hv.x; acc1 += wgt * hv.y;
    }
    float inv = 1.0f / (den + 1e-16f);
    float2 bv = *(const float2*)(bias + lane*2);
    float2 o; o.x = acc0 * inv + bv.x; o.y = acc1 * inv + bv.y;
    *(float2*)(outp + (size_t)node*128 + lane*2) = o;
}

// ---------------------------------------------------------------------------
// Final projection: out[n,2] = x3 @ W_o2[128,2] + b_o2, f32 out. Wave per node.
// ---------------------------------------------------------------------------
__global__ __launch_bounds__(256) void k_out(
    const float* __restrict__ x3, const float* __restrict__ Wo2,
    const float* __restrict__ bo2, float* __restrict__ outp, int n)
{
    int lane = threadIdx.x & 63, wave = threadIdx.x >> 6;
    int node = blockIdx.x * 4 + wave;
    if (node >= n) return;
    float xa = x3[(size_t)node*128 + lane];
    float xb = x3[(size_t)node*128 + 64 + lane];
    float s0 = xa * Wo2[lane*2]     + xb * Wo2[(lane + 64)*2];
    float s1 = xa * Wo2[lane*2 + 1] + xb * Wo2[(lane + 64)*2 + 1];
    #pragma unroll
    for (int ofs = 1; ofs <= 32; ofs <<= 1){
        s0 += __shfl_xor(s0, ofs);
        s1 += __shfl_xor(s1, ofs);
    }
    if (lane == 0){
        outp[(size_t)node*2]     = s0 + bo2[0];
        outp[(size_t)node*2 + 1] = s1 + bo2[1];
    }
}

// ---------------------------------------------------------------------------
// CSR build (dst-indexed): histogram, 3-stage exclusive scan, scatter.
// Edge reads use runtime stride st (1=int32, 2=int64 low words).
// ---------------------------------------------------------------------------
__global__ void k_hist(const int* __restrict__ ei32, const int* __restrict__ eflag,
                       int* __restrict__ deg, int e){
    int st = eflag[0];
    int i = blockIdx.x * 256 + threadIdx.x;
    if (i < e) atomicAdd(&deg[ei32[(size_t)st*(e + i)]], 1);
}
__global__ __launch_bounds__(256) void k_scan1(
    const int* __restrict__ deg, int* __restrict__ startv, int* __restrict__ bsum, int n)
{
    __shared__ int sd[256];
    int tid = threadIdx.x;
    int base = blockIdx.x * 2048 + tid * 8;
    int v[8]; int s = 0;
    #pragma unroll
    for (int i = 0; i < 8; ++i){
        int x = (base + i < n) ? deg[base + i] : 0;
        v[i] = s; s += x;
    }
    sd[tid] = s; __syncthreads();
    int own = s;
    for (int ofs = 1; ofs < 256; ofs <<= 1){
        int t = 0; if (tid >= ofs) t = sd[tid - ofs];
        __syncthreads(); sd[tid] += t; __syncthreads();
    }
    int excl = sd[tid] - own;
    #pragma unroll
    for (int i = 0; i < 8; ++i)
        if (base + i < n) startv[base + i] = excl + v[i];
    if (tid == 255) bsum[blockIdx.x] = sd[255];
}
__global__ void k_scan2(const int* __restrict__ bsum, int* __restrict__ bofs, int nb){
    if (threadIdx.x == 0 && blockIdx.x == 0){
        int run = 0;
        for (int i = 0; i < nb; ++i){ bofs[i] = run; run += bsum[i]; }
    }
}
__global__ void k_scan3(const int* __restrict__ bofs, int* __restrict__ startv,
                        int* __restrict__ cursor, int n){
    int i = blockIdx.x * 256 + threadIdx.x;
    if (i < n){
        int v = startv[i] + bofs[i >> 11];
        startv[i] = v; cursor[i] = v;
    }
}
__global__ void k_scatter(const int* __restrict__ ei32, const int* __restrict__ eflag,
                          int* __restrict__ cursor, int* __restrict__ col, int e){
    int st = eflag[0];
    int i = blockIdx.x * 256 + threadIdx.x;
    if (i < e){
        int s = ei32[(size_t)st*i];
        int d = ei32[(size_t)st*(e + i)];
        int pos = atomicAdd(&cursor[d], 1);
        col[pos] = s;
    }
}

// ---------------------------------------------------------------------------
extern "C" void kernel_launch(void* const* d_in, const int* in_sizes, int n_in,
                              void* d_out, int out_size, void* d_ws, size_t ws_size,
                              hipStream_t stream)
{
    const int n = in_sizes[0] / 768;     // 100000
    const int e = in_sizes[4] / 2;       // 1600000

    const float* des  = (const float*)d_in[0];
    const float* twt  = (const float*)d_in[1];
    const float* npv  = (const float*)d_in[2];
    const float* cpv  = (const float*)d_in[3];
    const int*   ei   = (const int*)d_in[4];
    const float* W_des = (const float*)d_in[5];
    const float* b_des = (const float*)d_in[6];
    const float* W_tw  = (const float*)d_in[7];
    const float* b_tw  = (const float*)d_in[8];
    const float* W_np  = (const float*)d_in[9];
    const float* b_np  = (const float*)d_in[10];
    const float* W_cp  = (const float*)d_in[11];
    const float* b_cp  = (const float*)d_in[12];
    const float* W_in  = (const float*)d_in[13];
    const float* b_in  = (const float*)d_in[14];
    const float* g1W   = (const float*)d_in[15];
    const float* g1as  = (const float*)d_in[16];
    const float* g1ad  = (const float*)d_in[17];
    const float* g1b   = (const float*)d_in[18];
    const float* g2W   = (const float*)d_in[19];
    const float* g2as  = (const float*)d_in[20];
    const float* g2ad  = (const float*)d_in[21];
    const float* g2b   = (const float*)d_in[22];
    const float* Wo1   = (const float*)d_in[23];
    const float* bo1   = (const float*)d_in[24];
    const float* Wo2   = (const float*)d_in[25];
    const float* bo2   = (const float*)d_in[26];

    // workspace layout (~114.5 MB)
    char* wp = (char*)d_ws;
    size_t off = 0;
    auto alloc = [&](size_t bytes) -> void* {
        void* p = (void*)(wp + off);
        off += (bytes + 255) & ~(size_t)255;
        return p;
    };
    int*            eflag = (int*)alloc(256);
    unsigned short* encW  = (unsigned short*)alloc((size_t)2*49152*2);
    unsigned short* midW  = (unsigned short*)alloc((size_t)4*32768*2);
    float* buf0   = (float*)alloc((size_t)n * 128 * 4);
    float* buf1   = (float*)alloc((size_t)n * 128 * 4);
    float* als1   = (float*)alloc((size_t)n * 4 * 4);
    float* ald1   = (float*)alloc((size_t)n * 4 * 4);
    float* als2   = (float*)alloc((size_t)n * 4);
    float* ald2   = (float*)alloc((size_t)n * 4);
    int*   deg    = (int*)alloc((size_t)n * 4);
    int*   startv = (int*)alloc((size_t)n * 4);
    int*   cursor = (int*)alloc((size_t)n * 4);
    int*   col    = (int*)alloc((size_t)e * 4);
    int*   bsum   = (int*)alloc(256 * 4);
    int*   bofs   = (int*)alloc(256 * 4);

    // --- prep: edge dtype flag + weight splitting ---
    k_detect<<<1, 64, 0, stream>>>(ei, eflag);
    k_prep_enc<<<(2*24576 + 255)/256, 256, 0, stream>>>(W_des, W_tw, encW);
    k_prep_mid<<<(4*16384 + 255)/256, 256, 0, stream>>>(W_in, g1W, g2W, Wo1, midW);

    // --- CSR build (rebuilt every call; ws re-poisoned by harness) ---
    hipMemsetAsync(deg, 0, (size_t)n * sizeof(int), stream);
    k_hist<<<(e + 255)/256, 256, 0, stream>>>(ei, eflag, deg, e);
    int nch = (n + 2047) / 2048;
    k_scan1<<<nch, 256, 0, stream>>>(deg, startv, bsum, n);
    k_scan2<<<1, 64, 0, stream>>>(bsum, bofs, nch);
    k_scan3<<<(n + 255)/256, 256, 0, stream>>>(bofs, startv, cursor, n);
    k_scatter<<<(e + 255)/256, 256, 0, stream>>>(ei, eflag, cursor, col, e);

    // --- encoders -> x0 (buf0) ---
    dim3 ge((n + 63)/64, 2);
    k_enc<<<ge, 256, 0, stream>>>(des, b_des, twt, b_tw, encW, buf0, n);
    k_npcp<<<(n + 255)/256, 256, 0, stream>>>(npv, W_np, b_np, cpv, W_cp, b_cp, buf0, n);

    // --- x = leaky(x0 @ W_in + b_in) -> buf1 ---
    k_mid<<<(n + 63)/64, 256, 0, stream>>>(buf0, midW,             b_in, buf1, n, 1);
    // --- GAT1: h1 = x @ gat1_W -> buf0; attention -> buf1 ---
    k_mid<<<(n + 63)/64, 256, 0, stream>>>(buf1, midW + 32768,     b_in, buf0, n, 0);
    k_al<<<(n + 3)/4, 256, 0, stream>>>(buf0, g1as, g1ad, als1, ald1, n, 4);
    k_edge4<<<(n + 3)/4, 256, 0, stream>>>(buf0, als1, ald1, startv, deg, col, g1b, buf1, n);
    // --- GAT2: h2 = out1 @ gat2_W -> buf0; attention -> buf1 ---
    k_mid<<<(n + 63)/64, 256, 0, stream>>>(buf1, midW + 2*32768,   b_in, buf0, n, 0);
    k_al<<<(n + 3)/4, 256, 0, stream>>>(buf0, g2as, g2ad, als2, ald2, n, 1);
    k_edge1<<<(n + 3)/4, 256, 0, stream>>>(buf0, als2, ald2, startv, deg, col, g2b, buf1, n);
    // --- x3 = leaky(out2 @ W_o1 + b_o1) -> buf0; out = x3 @ W_o2 + b_o2 ---
    k_mid<<<(n + 63)/64, 256, 0, stream>>>(buf1, midW + 3*32768,   bo1, buf0, n, 1);
    k_out<<<(n + 3)/4, 256, 0, stream>>>(buf0, Wo2, bo2, (float*)d_out, n);
}